// Round 14
// baseline (481.480 us; speedup 1.0000x reference)
//
#include <hip/hip_runtime.h>
#include <math.h>

#define BATCH   65536
#define DIM     64
#define HID     128
#define SPLIT   32
#define NBINS   8
#define PDIM    25          // 3*NBINS+1
#define NLAYERS 6
#define R_MIN   (-5.0f)
#define R_MAX   (5.0f)
#define MIN_BIN   1.0e-4f
#define MIN_SLOPE 1.0e-4f
#define SOFF      0.54116666f   // log(exp(1-MIN_SLOPE)-1)

#define ROWSW 16      // rows per wave
#define WAVES 4
#define MBLK  64      // rows per block
#define NT    256

#define N_W1  (HID*SPLIT)      // 4096
#define N_W2  (HID*HID)        // 16384
#define N_W4P (32*32*HID)      // 131072 (8 tb x 8 pq x 4 kt chunks of 512)
#define N_W4  (SPLIT*PDIM*HID) // 102400

typedef __attribute__((ext_vector_type(8))) short bf16x8;
typedef __attribute__((ext_vector_type(4))) float f32x4;

__device__ __forceinline__ short f2bf(float f) {
    unsigned u = __builtin_bit_cast(unsigned, f);
    unsigned r = u + 0x7FFFu + ((u >> 16) & 1u);   // RNE
    return (short)(r >> 16);
}

__device__ __forceinline__ unsigned pk2(float a, float b) {   // 2xf32 -> packed bf16 (RNE)
    unsigned r;
    asm("v_cvt_pk_bf16_f32 %0, %1, %2" : "=v"(r) : "v"(a), "v"(b));
    return r;
}

// act LDS layout: [group g = k>>2][row r][k&3] shorts, group stride 64 shorts.
__device__ __forceinline__ bf16x8 ldfrag(const short* base) {
    short4 lo = *reinterpret_cast<const short4*>(base);
    short4 hi = *reinterpret_cast<const short4*>(base + 64);
    bf16x8 a;
    a[0]=lo.x; a[1]=lo.y; a[2]=lo.z; a[3]=lo.w;
    a[4]=hi.x; a[5]=hi.y; a[6]=hi.z; a[7]=hi.w;
    return a;
}

// ---- weight conversion prologue (fragment packing, same as R5-R13) ----
__global__ void cvt_weights(const float* __restrict__ W1, const float* __restrict__ W2,
                            const float* __restrict__ W3, const float* __restrict__ W4,
                            const float* __restrict__ b4,
                            short* __restrict__ o1, short* __restrict__ o2,
                            short* __restrict__ o3, short* __restrict__ o4,
                            float* __restrict__ b4q) {
    const int stride = gridDim.x * blockDim.x;
    const int i0 = blockIdx.x * blockDim.x + threadIdx.x;
    for (int i = i0; i < NLAYERS*N_W1; i += stride) {
        const int L = i >> 12, rem = i & 4095;
        const int nt = rem >> 9, q = rem & 511;
        const int l = q >> 3, e = q & 7;
        o1[i] = f2bf(W1[L*N_W1 + (nt*16 + (l&15))*SPLIT + (l>>4)*8 + e]);
    }
    for (int i = i0; i < NLAYERS*N_W2; i += stride) {
        const int L = i >> 14, rem = i & 16383;
        const int c = rem >> 9, q = rem & 511;
        const int nt = c >> 2, kt = c & 3;
        const int l = q >> 3, e = q & 7;
        const int src = L*N_W2 + (nt*16 + (l&15))*HID + kt*32 + (l>>4)*8 + e;
        o2[i] = f2bf(W2[src]);
        o3[i] = f2bf(W3[src]);
    }
    for (int i = i0; i < NLAYERS*N_W4P; i += stride) {
        const int L = i >> 17, rem = i & (N_W4P - 1);
        const int c = rem >> 9, q = rem & 511;
        const int tb = c >> 5, pq = (c >> 2) & 7, kt = c & 3;
        const int l = q >> 3, e = q & 7;
        const int t = tb*4 + ((l & 15) >> 2);
        const int p = pq*4 + (l & 3);
        o4[i] = (p < PDIM)
              ? f2bf(W4[(size_t)L*N_W4 + (size_t)(t*PDIM + p)*HID + kt*32 + (l>>4)*8 + e])
              : (short)0;
    }
    for (int i = i0; i < NLAYERS*SPLIT*32; i += stride) {
        const int L = i >> 10, rem = i & 1023;
        const int t = rem >> 5, p = rem & 31;
        b4q[i] = (p < PDIM) ? b4[L*SPLIT*PDIM + t*PDIM + p] : 0.0f;
    }
}

// One coupling layer (R7 structure) with a 2-deep software pipeline in the
// W4+spline loop: while the spline of tile tb consumes cCur, tile tb+1's
// weight loads + MFMAs fill cNxt, interleaved at kt-group granularity so the
// load latency of each 7-fragment group is covered by one spline stage.
__global__ __launch_bounds__(NT, 4) void flow_layer(
    const float* xin, float* yout, float* logdet, const int first,
    const short* __restrict__ bW1, const float* __restrict__ b1,
    const short* __restrict__ bW2, const float* __restrict__ b2,
    const short* __restrict__ bW3, const float* __restrict__ b3,
    const short* __restrict__ bW4, const float* __restrict__ b4q,
    const int* __restrict__ mi, const int* __restrict__ ti)
{
    __shared__ short act[WAVES][32 * 64];         // 32 groups x 16 rows x 4 shorts
    __shared__ float xts[WAVES][ROWSW][33];       // spline inputs (f32)

    const int tid = threadIdx.x;
    const int wv  = tid >> 6;    // wave id
    const int l   = tid & 63;    // lane
    const int lr  = l & 15;      // row / col-in-tile
    const int lg  = l >> 4;      // 0..3
    const int rbase = blockIdx.x * MBLK + wv * ROWSW;

    short* const actw = &act[wv][0];

    // ---- gather: xm -> act groups 0..7 (bf16), xt -> xts (f32) ----
    {
        const int kcol = l & 31;
        const int mc = mi[kcol], tc = ti[kcol];
        const int r0 = l >> 5;                    // 0 or 1
        #pragma unroll
        for (int it = 0; it < 8; ++it) {
            const int r = r0 + it * 2;
            const float* row = xin + (size_t)(rbase + r) * DIM;
            const float mv = row[mc];
            actw[(kcol >> 2)*64 + r*4 + (kcol & 3)] = f2bf(mv);
            xts[wv][r][kcol] = row[tc];
            if (first) yout[(size_t)(rbase + r) * DIM + mc] = mv;  // copy-through (L0)
        }
    }

    // ================= h1 = relu(W1 @ xm^T + b1)  [K=32] =================
    {
        const bf16x8 afr0 = ldfrag(&actw[(2*lg)*64 + lr*4]);
        f32x4 c[8];
        #pragma unroll
        for (int nt = 0; nt < 8; ++nt) {
            const float4 bv = *reinterpret_cast<const float4*>(b1 + nt*16 + lg*4);
            c[nt] = (f32x4){bv.x, bv.y, bv.z, bv.w};
        }
        #pragma unroll
        for (int nt = 0; nt < 8; ++nt) {
            const bf16x8 wfr = *reinterpret_cast<const bf16x8*>(bW1 + (size_t)nt*512 + l*8);
            c[nt] = __builtin_amdgcn_mfma_f32_16x16x32_bf16(wfr, afr0, c[nt], 0, 0, 0);
        }
        #pragma unroll
        for (int nt = 0; nt < 8; ++nt) {
            const unsigned u0 = pk2(fmaxf(c[nt][0], 0.0f), fmaxf(c[nt][1], 0.0f));
            const unsigned u1 = pk2(fmaxf(c[nt][2], 0.0f), fmaxf(c[nt][3], 0.0f));
            *reinterpret_cast<uint2*>(&actw[(nt*4 + lg)*64 + lr*4]) = (uint2){u0, u1};
        }
    }

    // ================= h2 / h3  [K=128] =================
    #pragma unroll 1
    for (int ph = 0; ph < 2; ++ph) {
        const short* Wp = ph ? bW3 : bW2;
        const float* bp = ph ? b3  : b2;
        bf16x8 afr[4];
        #pragma unroll
        for (int kt = 0; kt < 4; ++kt)
            afr[kt] = ldfrag(&actw[(kt*8 + 2*lg)*64 + lr*4]);
        f32x4 c[8];
        #pragma unroll
        for (int nt = 0; nt < 8; ++nt) {
            const float4 bv = *reinterpret_cast<const float4*>(bp + nt*16 + lg*4);
            c[nt] = (f32x4){bv.x, bv.y, bv.z, bv.w};
        }
        #pragma unroll
        for (int kt = 0; kt < 4; ++kt)
            #pragma unroll
            for (int nt = 0; nt < 8; ++nt) {
                const bf16x8 wfr = *reinterpret_cast<const bf16x8*>(Wp + (size_t)(nt*4 + kt)*512 + l*8);
                c[nt] = __builtin_amdgcn_mfma_f32_16x16x32_bf16(wfr, afr[kt], c[nt], 0, 0, 0);
            }
        #pragma unroll
        for (int nt = 0; nt < 8; ++nt) {
            const unsigned u0 = pk2(fmaxf(c[nt][0], 0.0f), fmaxf(c[nt][1], 0.0f));
            const unsigned u1 = pk2(fmaxf(c[nt][2], 0.0f), fmaxf(c[nt][3], 0.0f));
            *reinterpret_cast<uint2*>(&actw[(nt*4 + lg)*64 + lr*4]) = (uint2){u0, u1};
        }
    }

    // ================= W4 params + RQS spline (2-deep pipeline) =============
    bf16x8 afr[4];
    #pragma unroll
    for (int kt = 0; kt < 4; ++kt)
        afr[kt] = ldfrag(&actw[(kt*8 + 2*lg)*64 + lr*4]);

    float ldacc = 0.0f;

    auto loadgrp = [&](bf16x8* wfr, int tb, int kt) {
        #pragma unroll
        for (int pq = 0; pq < 7; ++pq)
            wfr[pq] = *reinterpret_cast<const bf16x8*>(
                bW4 + (size_t)((tb*8 + pq)*4 + kt)*512 + l*8);
    };
    auto mfmagrp = [&](f32x4* c, const bf16x8* wfr, int kt) {
        #pragma unroll
        for (int pq = 0; pq < 7; ++pq)
            c[pq] = __builtin_amdgcn_mfma_f32_16x16x32_bf16(wfr[pq], afr[kt], c[pq], 0, 0, 0);
    };
    auto biasinit = [&](f32x4* c, int tb) {
        const int t = tb*4 + lg;
        #pragma unroll
        for (int pq = 0; pq < 7; ++pq) {
            const float4 bv = *reinterpret_cast<const float4*>(b4q + t*32 + pq*4);
            c[pq] = (f32x4){bv.x, bv.y, bv.z, bv.w};
        }
    };

    // spline(tb) on cCur interleaved with fill(tb+1) into cNxt
    auto stage = [&](f32x4* cC, f32x4* cN, const int tb, const bool doNext) {
        bf16x8 wfr[7];
        if (doNext) { biasinit(cN, tb + 1); loadgrp(wfr, tb + 1, 0); }

        // ---- S1: exps + scales (p[i] = cC[i>>2][i&3], static idx) ----
        float wd[NBINS], hg[NBINS];
        #pragma unroll
        for (int i = 0; i < NBINS; ++i) wd[i] = __expf(cC[i>>2][i&3]);
        #pragma unroll
        for (int i = 0; i < NBINS; ++i) hg[i] = __expf(cC[(NBINS+i)>>2][(NBINS+i)&3]);
        const float sw = ((wd[0]+wd[1]) + (wd[2]+wd[3])) + ((wd[4]+wd[5]) + (wd[6]+wd[7]));
        const float sh = ((hg[0]+hg[1]) + (hg[2]+hg[3])) + ((hg[4]+hg[5]) + (hg[6]+hg[7]));
        const float scw = __fdividef((R_MAX - R_MIN) - NBINS * MIN_BIN, sw);
        const float sch = __fdividef((R_MAX - R_MIN) - NBINS * MIN_BIN, sh);
        #pragma unroll
        for (int i = 0; i < NBINS; ++i) { wd[i] = wd[i]*scw + MIN_BIN; hg[i] = hg[i]*sch + MIN_BIN; }

        if (doNext) { mfmagrp(cN, wfr, 0); loadgrp(wfr, tb + 1, 1); }

        // ---- S2: cumsum + knot select ----
        const float x = xts[wv][lr][tb*4 + lg];
        float cx = R_MIN, cy = R_MIN;
        float x_k = R_MIN, y_k = R_MIN, wsel = wd[0], hsel = hg[0];
        float z0 = cC[4][0], z1 = cC[4][1];
        #pragma unroll
        for (int i = 1; i < NBINS; ++i) {
            cx += wd[i-1]; cy += hg[i-1];
            const bool tk = (cx <= x);
            x_k  = tk ? cx : x_k;
            y_k  = tk ? cy : y_k;
            wsel = tk ? wd[i] : wsel;
            hsel = tk ? hg[i] : hsel;
            z0   = tk ? cC[(16+i)>>2][(16+i)&3] : z0;
            z1   = tk ? cC[(17+i)>>2][(17+i)&3] : z1;
        }

        if (doNext) { mfmagrp(cN, wfr, 1); loadgrp(wfr, tb + 1, 2); }

        // ---- S3: softplus(4) + rational ----
        auto sp = [](float v) {
            const float z = v + SOFF;
            return ((z > 15.0f) ? z : __logf(1.0f + __expf(z))) + MIN_SLOPE;
        };
        const float d_k = sp(z0), d_k1 = sp(z1);
        const float sl0 = sp(cC[4][0]), sl8 = sp(cC[6][0]);

        const float invw = __fdividef(1.0f, wsel);
        float xi = (x - x_k) * invw;
        xi = fminf(fmaxf(xi, 0.0f), 1.0f);
        const float s    = hsel * invw;
        const float xi1m = 1.0f - xi;
        const float q    = xi * xi1m;
        const float num  = s * xi * xi + d_k * q;
        const float den  = s + (d_k1 + d_k - 2.0f * s) * q;
        const float invden = __fdividef(1.0f, den);
        const float y_sp = y_k + hsel * num * invden;
        const float deriv = s * s * (d_k1 * xi * xi + 2.0f * s * q + d_k * xi1m * xi1m)
                            * invden * invden;

        if (doNext) { mfmagrp(cN, wfr, 2); loadgrp(wfr, tb + 1, 3); }

        // ---- S4: tails + log + store ----
        const bool below = x < R_MIN;
        const bool above = x > R_MAX;
        const float yv = below ? ((x - R_MIN) * sl0 + R_MIN)
                       : (above ? ((x - R_MAX) * sl8 + R_MAX) : y_sp);
        const float dv = below ? sl0 : (above ? sl8 : deriv);
        ldacc += __logf(dv);
        yout[(size_t)(rbase + lr) * DIM + ti[tb*4 + lg]] = yv;

        if (doNext) { mfmagrp(cN, wfr, 3); }
    };

    f32x4 cA[7], cB[7];
    {   // prologue: fill cA with tile 0 (plain)
        bf16x8 wfr[7];
        biasinit(cA, 0);
        #pragma unroll
        for (int kt = 0; kt < 4; ++kt) { loadgrp(wfr, 0, kt); mfmagrp(cA, wfr, kt); }
    }
    #pragma unroll 1
    for (int tb = 0; tb < 8; tb += 2) {
        stage(cA, cB, tb,     true);         // spline(tb)   ∥ fill(tb+1)
        stage(cB, cA, tb + 1, tb + 1 < 7);   // spline(tb+1) ∥ fill(tb+2)
    }

    // per-row logdet: reduce over the 4 lane-groups (fixed order)
    ldacc += __shfl_xor(ldacc, 16, 64);
    ldacc += __shfl_xor(ldacc, 32, 64);
    if (l < 16) {
        const int row = rbase + lr;
        if (first) logdet[row] = ldacc;
        else       logdet[row] += ldacc;
    }
}

extern "C" void kernel_launch(void* const* d_in, const int* in_sizes, int n_in,
                              void* d_out, int out_size, void* d_ws, size_t ws_size,
                              hipStream_t stream) {
    const float* x  = (const float*)d_in[0];
    const float* W1 = (const float*)d_in[1];
    const float* b1 = (const float*)d_in[2];
    const float* W2 = (const float*)d_in[3];
    const float* b2 = (const float*)d_in[4];
    const float* W3 = (const float*)d_in[5];
    const float* b3 = (const float*)d_in[6];
    const float* W4 = (const float*)d_in[7];
    const float* b4 = (const float*)d_in[8];
    const int*   mi = (const int*)d_in[9];
    const int*   ti = (const int*)d_in[10];

    float* y      = (float*)d_out;
    float* logdet = y + (size_t)BATCH * DIM;

    short* bW1 = (short*)d_ws;
    short* bW2 = bW1 + NLAYERS * N_W1;
    short* bW3 = bW2 + NLAYERS * N_W2;
    short* bW4 = bW3 + NLAYERS * N_W2;
    float* b4q = (float*)(bW4 + (size_t)NLAYERS * N_W4P);

    cvt_weights<<<512, 256, 0, stream>>>(W1, W2, W3, W4, b4, bW1, bW2, bW3, bW4, b4q);

    dim3 grid(BATCH / MBLK), block(NT);
    for (int L = 0; L < NLAYERS; ++L) {
        flow_layer<<<grid, block, 0, stream>>>(
            (L == 0) ? x : y, y, logdet, (L == 0) ? 1 : 0,
            bW1 + (size_t)L * N_W1, b1 + L * HID,
            bW2 + (size_t)L * N_W2, b2 + L * HID,
            bW3 + (size_t)L * N_W2, b3 + L * HID,
            bW4 + (size_t)L * N_W4P, b4q + (size_t)L * SPLIT * 32,
            mi + L * SPLIT, ti + L * SPLIT);
    }
}

// Round 15
// 376.295 us; speedup vs baseline: 1.2795x; 1.2795x over previous
//
#include <hip/hip_runtime.h>
#include <math.h>

#define BATCH   65536
#define DIM     64
#define HID     128
#define SPLIT   32
#define NBINS   8
#define PDIM    25          // 3*NBINS+1
#define NLAYERS 6
#define R_MIN   (-5.0f)
#define R_MAX   (5.0f)
#define MIN_BIN   1.0e-4f
#define MIN_SLOPE 1.0e-4f
#define SOFF      0.54116666f   // log(exp(1-MIN_SLOPE)-1)

#define ROWSW 16      // rows per wave
#define WAVES 4
#define MBLK  64      // rows per block
#define NT    256

#define N_W1  (HID*SPLIT)      // 4096
#define N_W2  (HID*HID)        // 16384
#define N_W4P (32*32*HID)      // 131072 (8 tb x 8 pq x 4 kt chunks of 512)
#define N_W4  (SPLIT*PDIM*HID) // 102400

typedef __attribute__((ext_vector_type(8))) short bf16x8;
typedef __attribute__((ext_vector_type(4))) float f32x4;

__device__ __forceinline__ short f2bf(float f) {
    unsigned u = __builtin_bit_cast(unsigned, f);
    unsigned r = u + 0x7FFFu + ((u >> 16) & 1u);   // RNE
    return (short)(r >> 16);
}

__device__ __forceinline__ unsigned pk2(float a, float b) {   // 2xf32 -> packed bf16 (RNE)
    unsigned r;
    asm("v_cvt_pk_bf16_f32 %0, %1, %2" : "=v"(r) : "v"(a), "v"(b));
    return r;
}

// act LDS layout: [group g = k>>2][row r][k&3] shorts, group stride 64 shorts.
__device__ __forceinline__ bf16x8 ldfrag(const short* base) {
    short4 lo = *reinterpret_cast<const short4*>(base);
    short4 hi = *reinterpret_cast<const short4*>(base + 64);
    bf16x8 a;
    a[0]=lo.x; a[1]=lo.y; a[2]=lo.z; a[3]=lo.w;
    a[4]=hi.x; a[5]=hi.y; a[6]=hi.z; a[7]=hi.w;
    return a;
}

// ---- weight conversion prologue (fragment packing, same as R5-R14) ----
__global__ void cvt_weights(const float* __restrict__ W1, const float* __restrict__ W2,
                            const float* __restrict__ W3, const float* __restrict__ W4,
                            const float* __restrict__ b4,
                            short* __restrict__ o1, short* __restrict__ o2,
                            short* __restrict__ o3, short* __restrict__ o4,
                            float* __restrict__ b4q) {
    const int stride = gridDim.x * blockDim.x;
    const int i0 = blockIdx.x * blockDim.x + threadIdx.x;
    for (int i = i0; i < NLAYERS*N_W1; i += stride) {
        const int L = i >> 12, rem = i & 4095;
        const int nt = rem >> 9, q = rem & 511;
        const int l = q >> 3, e = q & 7;
        o1[i] = f2bf(W1[L*N_W1 + (nt*16 + (l&15))*SPLIT + (l>>4)*8 + e]);
    }
    for (int i = i0; i < NLAYERS*N_W2; i += stride) {
        const int L = i >> 14, rem = i & 16383;
        const int c = rem >> 9, q = rem & 511;
        const int nt = c >> 2, kt = c & 3;
        const int l = q >> 3, e = q & 7;
        const int src = L*N_W2 + (nt*16 + (l&15))*HID + kt*32 + (l>>4)*8 + e;
        o2[i] = f2bf(W2[src]);
        o3[i] = f2bf(W3[src]);
    }
    for (int i = i0; i < NLAYERS*N_W4P; i += stride) {
        const int L = i >> 17, rem = i & (N_W4P - 1);
        const int c = rem >> 9, q = rem & 511;
        const int tb = c >> 5, pq = (c >> 2) & 7, kt = c & 3;
        const int l = q >> 3, e = q & 7;
        const int t = tb*4 + ((l & 15) >> 2);
        const int p = pq*4 + (l & 3);
        o4[i] = (p < PDIM)
              ? f2bf(W4[(size_t)L*N_W4 + (size_t)(t*PDIM + p)*HID + kt*32 + (l>>4)*8 + e])
              : (short)0;
    }
    for (int i = i0; i < NLAYERS*SPLIT*32; i += stride) {
        const int L = i >> 10, rem = i & 1023;
        const int t = rem >> 5, p = rem & 31;
        b4q[i] = (p < PDIM) ? b4[L*SPLIT*PDIM + t*PDIM + p] : 0.0f;
    }
}

// One coupling layer (R7 structure) with a 2-deep software pipeline in the
// W4+spline loop. __launch_bounds__(NT,2): 256-VGPR budget so the pipeline
// buffers (cA/cB + wfr) live in registers -- R14's (NT,4)=128 cap spilled
// them to scratch (WRITE_SIZE tripled) and invalidated the experiment.
__global__ __launch_bounds__(NT, 2) void flow_layer(
    const float* xin, float* yout, float* logdet, const int first,
    const short* __restrict__ bW1, const float* __restrict__ b1,
    const short* __restrict__ bW2, const float* __restrict__ b2,
    const short* __restrict__ bW3, const float* __restrict__ b3,
    const short* __restrict__ bW4, const float* __restrict__ b4q,
    const int* __restrict__ mi, const int* __restrict__ ti)
{
    __shared__ short act[WAVES][32 * 64];         // 32 groups x 16 rows x 4 shorts
    __shared__ float xts[WAVES][ROWSW][33];       // spline inputs (f32)

    const int tid = threadIdx.x;
    const int wv  = tid >> 6;    // wave id
    const int l   = tid & 63;    // lane
    const int lr  = l & 15;      // row / col-in-tile
    const int lg  = l >> 4;      // 0..3
    const int rbase = blockIdx.x * MBLK + wv * ROWSW;

    short* const actw = &act[wv][0];

    // ---- gather: xm -> act groups 0..7 (bf16), xt -> xts (f32) ----
    {
        const int kcol = l & 31;
        const int mc = mi[kcol], tc = ti[kcol];
        const int r0 = l >> 5;                    // 0 or 1
        #pragma unroll
        for (int it = 0; it < 8; ++it) {
            const int r = r0 + it * 2;
            const float* row = xin + (size_t)(rbase + r) * DIM;
            const float mv = row[mc];
            actw[(kcol >> 2)*64 + r*4 + (kcol & 3)] = f2bf(mv);
            xts[wv][r][kcol] = row[tc];
            if (first) yout[(size_t)(rbase + r) * DIM + mc] = mv;  // copy-through (L0)
        }
    }

    // ================= h1 = relu(W1 @ xm^T + b1)  [K=32] =================
    {
        const bf16x8 afr0 = ldfrag(&actw[(2*lg)*64 + lr*4]);
        f32x4 c[8];
        #pragma unroll
        for (int nt = 0; nt < 8; ++nt) {
            const float4 bv = *reinterpret_cast<const float4*>(b1 + nt*16 + lg*4);
            c[nt] = (f32x4){bv.x, bv.y, bv.z, bv.w};
        }
        #pragma unroll
        for (int nt = 0; nt < 8; ++nt) {
            const bf16x8 wfr = *reinterpret_cast<const bf16x8*>(bW1 + (size_t)nt*512 + l*8);
            c[nt] = __builtin_amdgcn_mfma_f32_16x16x32_bf16(wfr, afr0, c[nt], 0, 0, 0);
        }
        #pragma unroll
        for (int nt = 0; nt < 8; ++nt) {
            const unsigned u0 = pk2(fmaxf(c[nt][0], 0.0f), fmaxf(c[nt][1], 0.0f));
            const unsigned u1 = pk2(fmaxf(c[nt][2], 0.0f), fmaxf(c[nt][3], 0.0f));
            *reinterpret_cast<uint2*>(&actw[(nt*4 + lg)*64 + lr*4]) = (uint2){u0, u1};
        }
    }

    // ================= h2 / h3  [K=128] =================
    #pragma unroll 1
    for (int ph = 0; ph < 2; ++ph) {
        const short* Wp = ph ? bW3 : bW2;
        const float* bp = ph ? b3  : b2;
        bf16x8 afr[4];
        #pragma unroll
        for (int kt = 0; kt < 4; ++kt)
            afr[kt] = ldfrag(&actw[(kt*8 + 2*lg)*64 + lr*4]);
        f32x4 c[8];
        #pragma unroll
        for (int nt = 0; nt < 8; ++nt) {
            const float4 bv = *reinterpret_cast<const float4*>(bp + nt*16 + lg*4);
            c[nt] = (f32x4){bv.x, bv.y, bv.z, bv.w};
        }
        #pragma unroll
        for (int kt = 0; kt < 4; ++kt)
            #pragma unroll
            for (int nt = 0; nt < 8; ++nt) {
                const bf16x8 wfr = *reinterpret_cast<const bf16x8*>(Wp + (size_t)(nt*4 + kt)*512 + l*8);
                c[nt] = __builtin_amdgcn_mfma_f32_16x16x32_bf16(wfr, afr[kt], c[nt], 0, 0, 0);
            }
        #pragma unroll
        for (int nt = 0; nt < 8; ++nt) {
            const unsigned u0 = pk2(fmaxf(c[nt][0], 0.0f), fmaxf(c[nt][1], 0.0f));
            const unsigned u1 = pk2(fmaxf(c[nt][2], 0.0f), fmaxf(c[nt][3], 0.0f));
            *reinterpret_cast<uint2*>(&actw[(nt*4 + lg)*64 + lr*4]) = (uint2){u0, u1};
        }
    }

    // ================= W4 params + RQS spline (2-deep pipeline) =============
    bf16x8 afr[4];
    #pragma unroll
    for (int kt = 0; kt < 4; ++kt)
        afr[kt] = ldfrag(&actw[(kt*8 + 2*lg)*64 + lr*4]);

    float ldacc = 0.0f;

    auto loadgrp4 = [&](bf16x8* wfr, int tb, int kt) {   // pq 0..3
        #pragma unroll
        for (int pq = 0; pq < 4; ++pq)
            wfr[pq] = *reinterpret_cast<const bf16x8*>(
                bW4 + (size_t)((tb*8 + pq)*4 + kt)*512 + l*8);
    };
    auto loadgrp3 = [&](bf16x8* wfr, int tb, int kt) {   // pq 4..6
        #pragma unroll
        for (int pq = 0; pq < 3; ++pq)
            wfr[pq] = *reinterpret_cast<const bf16x8*>(
                bW4 + (size_t)((tb*8 + 4 + pq)*4 + kt)*512 + l*8);
    };
    auto mfmagrp4 = [&](f32x4* c, const bf16x8* wfr, int kt) {
        #pragma unroll
        for (int pq = 0; pq < 4; ++pq)
            c[pq] = __builtin_amdgcn_mfma_f32_16x16x32_bf16(wfr[pq], afr[kt], c[pq], 0, 0, 0);
    };
    auto mfmagrp3 = [&](f32x4* c, const bf16x8* wfr, int kt) {
        #pragma unroll
        for (int pq = 0; pq < 3; ++pq)
            c[4+pq] = __builtin_amdgcn_mfma_f32_16x16x32_bf16(wfr[pq], afr[kt], c[4+pq], 0, 0, 0);
    };
    auto biasinit = [&](f32x4* c, int tb) {
        const int t = tb*4 + lg;
        #pragma unroll
        for (int pq = 0; pq < 7; ++pq) {
            const float4 bv = *reinterpret_cast<const float4*>(b4q + t*32 + pq*4);
            c[pq] = (f32x4){bv.x, bv.y, bv.z, bv.w};
        }
    };

    // spline(tb) on cC interleaved with fill(tb+1) into cN; loads split 4+3
    // per kt so at most 4 fragments (16 VGPR) are in flight at once.
    auto stage = [&](f32x4* cC, f32x4* cN, const int tb, const bool doNext) {
        bf16x8 wfr[4];
        if (doNext) { biasinit(cN, tb + 1); loadgrp4(wfr, tb + 1, 0); }

        // ---- S1: exps + scales ----
        float wd[NBINS], hg[NBINS];
        #pragma unroll
        for (int i = 0; i < NBINS; ++i) wd[i] = __expf(cC[i>>2][i&3]);
        #pragma unroll
        for (int i = 0; i < NBINS; ++i) hg[i] = __expf(cC[(NBINS+i)>>2][(NBINS+i)&3]);
        const float sw = ((wd[0]+wd[1]) + (wd[2]+wd[3])) + ((wd[4]+wd[5]) + (wd[6]+wd[7]));
        const float sh = ((hg[0]+hg[1]) + (hg[2]+hg[3])) + ((hg[4]+hg[5]) + (hg[6]+hg[7]));
        const float scw = __fdividef((R_MAX - R_MIN) - NBINS * MIN_BIN, sw);
        const float sch = __fdividef((R_MAX - R_MIN) - NBINS * MIN_BIN, sh);
        #pragma unroll
        for (int i = 0; i < NBINS; ++i) { wd[i] = wd[i]*scw + MIN_BIN; hg[i] = hg[i]*sch + MIN_BIN; }

        if (doNext) { mfmagrp4(cN, wfr, 0); loadgrp3(wfr, tb + 1, 0); }

        // ---- S2: cumsum + knot select ----
        const float x = xts[wv][lr][tb*4 + lg];
        float cx = R_MIN, cy = R_MIN;
        float x_k = R_MIN, y_k = R_MIN, wsel = wd[0], hsel = hg[0];
        float z0 = cC[4][0], z1 = cC[4][1];
        #pragma unroll
        for (int i = 1; i < NBINS; ++i) {
            cx += wd[i-1]; cy += hg[i-1];
            const bool tk = (cx <= x);
            x_k  = tk ? cx : x_k;
            y_k  = tk ? cy : y_k;
            wsel = tk ? wd[i] : wsel;
            hsel = tk ? hg[i] : hsel;
            z0   = tk ? cC[(16+i)>>2][(16+i)&3] : z0;
            z1   = tk ? cC[(17+i)>>2][(17+i)&3] : z1;
        }

        if (doNext) { mfmagrp3(cN, wfr, 0); loadgrp4(wfr, tb + 1, 1); }

        // ---- S3a: softplus(4) ----
        auto sp = [](float v) {
            const float z = v + SOFF;
            return ((z > 15.0f) ? z : __logf(1.0f + __expf(z))) + MIN_SLOPE;
        };
        const float d_k = sp(z0), d_k1 = sp(z1);
        const float sl0 = sp(cC[4][0]), sl8 = sp(cC[6][0]);

        if (doNext) { mfmagrp4(cN, wfr, 1); loadgrp3(wfr, tb + 1, 1); }

        // ---- S3b: rational ----
        const float invw = __fdividef(1.0f, wsel);
        float xi = (x - x_k) * invw;
        xi = fminf(fmaxf(xi, 0.0f), 1.0f);
        const float s    = hsel * invw;
        const float xi1m = 1.0f - xi;
        const float q    = xi * xi1m;
        const float num  = s * xi * xi + d_k * q;
        const float den  = s + (d_k1 + d_k - 2.0f * s) * q;
        const float invden = __fdividef(1.0f, den);
        const float y_sp = y_k + hsel * num * invden;
        const float deriv = s * s * (d_k1 * xi * xi + 2.0f * s * q + d_k * xi1m * xi1m)
                            * invden * invden;

        if (doNext) { mfmagrp3(cN, wfr, 1); loadgrp4(wfr, tb + 1, 2); }

        // ---- S4: tails + log + store ----
        const bool below = x < R_MIN;
        const bool above = x > R_MAX;
        const float yv = below ? ((x - R_MIN) * sl0 + R_MIN)
                       : (above ? ((x - R_MAX) * sl8 + R_MAX) : y_sp);
        const float dv = below ? sl0 : (above ? sl8 : deriv);
        ldacc += __logf(dv);
        yout[(size_t)(rbase + lr) * DIM + ti[tb*4 + lg]] = yv;

        if (doNext) {
            mfmagrp4(cN, wfr, 2); loadgrp3(wfr, tb + 1, 2);
            mfmagrp3(cN, wfr, 2); loadgrp4(wfr, tb + 1, 3);
            mfmagrp4(cN, wfr, 3); loadgrp3(wfr, tb + 1, 3);
            mfmagrp3(cN, wfr, 3);
        }
    };

    f32x4 cA[7], cB[7];
    {   // prologue: fill cA with tile 0 (plain)
        bf16x8 w4f[4], w3f[3];
        biasinit(cA, 0);
        #pragma unroll
        for (int kt = 0; kt < 4; ++kt) {
            loadgrp4(w4f, 0, kt); mfmagrp4(cA, w4f, kt);
            loadgrp3(w3f, 0, kt); mfmagrp3(cA, w3f, kt);
        }
    }
    #pragma unroll 1
    for (int tb = 0; tb < 8; tb += 2) {
        stage(cA, cB, tb,     true);         // spline(tb)   ∥ fill(tb+1)
        stage(cB, cA, tb + 1, tb + 1 < 7);   // spline(tb+1) ∥ fill(tb+2)
    }

    // per-row logdet: reduce over the 4 lane-groups (fixed order)
    ldacc += __shfl_xor(ldacc, 16, 64);
    ldacc += __shfl_xor(ldacc, 32, 64);
    if (l < 16) {
        const int row = rbase + lr;
        if (first) logdet[row] = ldacc;
        else       logdet[row] += ldacc;
    }
}

extern "C" void kernel_launch(void* const* d_in, const int* in_sizes, int n_in,
                              void* d_out, int out_size, void* d_ws, size_t ws_size,
                              hipStream_t stream) {
    const float* x  = (const float*)d_in[0];
    const float* W1 = (const float*)d_in[1];
    const float* b1 = (const float*)d_in[2];
    const float* W2 = (const float*)d_in[3];
    const float* b2 = (const float*)d_in[4];
    const float* W3 = (const float*)d_in[5];
    const float* b3 = (const float*)d_in[6];
    const float* W4 = (const float*)d_in[7];
    const float* b4 = (const float*)d_in[8];
    const int*   mi = (const int*)d_in[9];
    const int*   ti = (const int*)d_in[10];

    float* y      = (float*)d_out;
    float* logdet = y + (size_t)BATCH * DIM;

    short* bW1 = (short*)d_ws;
    short* bW2 = bW1 + NLAYERS * N_W1;
    short* bW3 = bW2 + NLAYERS * N_W2;
    short* bW4 = bW3 + NLAYERS * N_W2;
    float* b4q = (float*)(bW4 + (size_t)NLAYERS * N_W4P);

    cvt_weights<<<512, 256, 0, stream>>>(W1, W2, W3, W4, b4, bW1, bW2, bW3, bW4, b4q);

    dim3 grid(BATCH / MBLK), block(NT);
    for (int L = 0; L < NLAYERS; ++L) {
        flow_layer<<<grid, block, 0, stream>>>(
            (L == 0) ? x : y, y, logdet, (L == 0) ? 1 : 0,
            bW1 + (size_t)L * N_W1, b1 + L * HID,
            bW2 + (size_t)L * N_W2, b2 + L * HID,
            bW3 + (size_t)L * N_W2, b3 + L * HID,
            bW4 + (size_t)L * N_W4P, b4q + (size_t)L * SPLIT * 32,
            mi + L * SPLIT, ti + L * SPLIT);
    }
}